// Round 1
// baseline (249.428 us; speedup 1.0000x reference)
//
#include <hip/hip_runtime.h>
#include <stdint.h>

#define E2V     600000
#define NNODES  50000
#define NENT    100000
#define UCNT    500
#define NTYPE   400
#define DIN     200
#define DOUT    100
#define NB      16
#define CHUNK   16

static constexpr size_t align256(size_t x){ return (x + 255) & ~size_t(255); }
static constexpr size_t OFF_OVR  = 0;                                   // 50000 int, init -1
static constexpr size_t OFF_TCNT = align256(OFF_OVR + (size_t)NNODES*4);// 400 int
static constexpr size_t OFF_TCUR = OFF_TCNT + NTYPE*4;                  // 400 int
static constexpr size_t OFF_CNT  = OFF_TCUR + NTYPE*4;                  // 500 int
static constexpr size_t OFF_NF   = OFF_CNT + UCNT*4;                    // 1 int
static constexpr size_t OFF_AGGM = align256(OFF_NF + 4);                // 500*100 f32
static constexpr size_t OFF_AGGS = OFF_AGGM + (size_t)UCNT*DOUT*4;      // 500*100 f32
static constexpr size_t ZERO_BEG = OFF_TCNT;
static constexpr size_t ZERO_END = OFF_AGGS + (size_t)UCNT*DOUT*4;
static constexpr size_t OFF_FILT = align256(ZERO_END);                  // 600000 int
static constexpr size_t OFF_SORT = OFF_FILT + (size_t)E2V*4;            // 600000 int
static constexpr size_t OFF_TOFF = OFF_SORT + (size_t)E2V*4;            // 401 int
static constexpr size_t OFF_WMU  = align256(OFF_TOFF + (NTYPE+1)*4);    // 400*20000 bf16
static constexpr size_t OFF_WSIG = OFF_WMU + (size_t)NTYPE*20000*2;
static constexpr size_t NEED_BIG = OFF_WSIG + (size_t)NTYPE*20000*2;    // ~37.4 MB

__device__ __forceinline__ unsigned short f32_to_bf16(float f){
    uint32_t u = __float_as_uint(f);
    uint32_t r = (u + 0x7FFFu + ((u >> 16) & 1u)) >> 16;
    return (unsigned short)r;
}
__device__ __forceinline__ float bf16_to_f32(unsigned short h){
    return __uint_as_float(((uint32_t)h) << 16);
}

// ---- K2: scatter unseen positions (last-wins via atomicMax) ----
__global__ void k_scatter(const int* __restrict__ unseen_index, int* __restrict__ ovr){
    int u = threadIdx.x + blockIdx.x * blockDim.x;
    if (u < UCNT) atomicMax(&ovr[unseen_index[u]], u);
}

// ---- K3: filter edges with dst in unseen set; histogram types; count per slot ----
__global__ void k_filter(const int* __restrict__ eidx, const int* __restrict__ etype,
                         const int* __restrict__ ovr,
                         int* __restrict__ filtered, int* __restrict__ nfilt,
                         int* __restrict__ tcnt, int* __restrict__ cnt){
    int e = threadIdx.x + blockIdx.x * blockDim.x;
    if (e >= E2V) return;
    int d = eidx[E2V + e];
    int slot = ovr[d];
    if (slot >= 0){
        int pos = atomicAdd(nfilt, 1);
        filtered[pos] = e;
        atomicAdd(&tcnt[etype[e]], 1);
        atomicAdd(&cnt[slot], 1);
    }
}

// ---- K4: exclusive prefix over 400 type counts (single block) ----
__global__ void k_prefix(const int* __restrict__ tcnt, int* __restrict__ toff){
    __shared__ int a[512], b[512];
    int t = threadIdx.x;
    a[t] = (t < NTYPE) ? tcnt[t] : 0;
    __syncthreads();
    int* src = a; int* dst = b;
    for (int off = 1; off < 512; off <<= 1){
        dst[t] = src[t] + ((t >= off) ? src[t - off] : 0);
        __syncthreads();
        int* tmp = src; src = dst; dst = tmp;
    }
    if (t < NTYPE) toff[t + 1] = src[t];
    if (t == 0) toff[0] = 0;
}

// ---- K5: bin filtered edges by type ----
__global__ void k_bin(const int* __restrict__ filtered, const int* __restrict__ nfilt,
                      const int* __restrict__ etype, const int* __restrict__ toff,
                      int* __restrict__ tcur, int* __restrict__ sorted_e){
    int i = threadIdx.x + blockIdx.x * blockDim.x;
    if (i >= nfilt[0]) return;
    int e = filtered[i];
    int t = etype[e];
    int pos = toff[t] + atomicAdd(&tcur[t], 1);
    sorted_e[pos] = e;
}

// ---- K6: build W[t] = sum_b att[t,b]*basis[b]  (bf16, both branches) ----
__global__ void k_buildW(const float* __restrict__ att_mu, const float* __restrict__ att_sig,
                         const float* __restrict__ basis_mu, const float* __restrict__ basis_sig,
                         unsigned short* __restrict__ Wmu, unsigned short* __restrict__ Wsig){
    __shared__ float sAm[100*NB], sAs[100*NB];
    int tb = blockIdx.y * 100;
    for (int q = threadIdx.x; q < 100*NB; q += 256){
        sAm[q] = att_mu[tb*NB + q];
        sAs[q] = att_sig[tb*NB + q];
    }
    __syncthreads();
    int pos = blockIdx.x * 256 + threadIdx.x;
    if (pos >= DIN*DOUT) return;
    float bm[NB], bs[NB];
    #pragma unroll
    for (int b = 0; b < NB; ++b){
        bm[b] = basis_mu[b*DIN*DOUT + pos];
        bs[b] = basis_sig[b*DIN*DOUT + pos];
    }
    for (int tl = 0; tl < 100; ++tl){
        float wm = 0.f, wsg = 0.f;
        #pragma unroll
        for (int b = 0; b < NB; ++b){
            wm  += sAm[tl*NB + b] * bm[b];
            wsg += sAs[tl*NB + b] * bs[b];
        }
        size_t o = (size_t)(tb + tl) * (DIN*DOUT) + pos;
        Wmu[o]  = f32_to_bf16(wm);
        Wsig[o] = f32_to_bf16(wsg);
    }
}

// ---- K7: per-type messages -> atomic agg.  BUILD=true: make W in LDS from basis. ----
template<bool BUILD>
__global__ __launch_bounds__(256) void k_msg(
        const int* __restrict__ toff, const int* __restrict__ sorted_e,
        const int* __restrict__ ovr, const int* __restrict__ eidx,
        const int* __restrict__ rel_index, const int* __restrict__ node_id,
        const float* __restrict__ ent, const float* __restrict__ unseen_emb,
        const float* __restrict__ rel_table,
        const float* __restrict__ att_mu, const float* __restrict__ att_sig,
        const float* __restrict__ basis_mu, const float* __restrict__ basis_sig,
        const unsigned short* __restrict__ Wmu, const unsigned short* __restrict__ Wsig,
        float* __restrict__ agg_mu, float* __restrict__ agg_sig){
    int t = blockIdx.x;
    int start = toff[t], end = toff[t+1];
    if (start >= end) return;
    __shared__ __align__(16) unsigned short sW[DIN*DOUT];
    __shared__ float sM[CHUNK][DIN];
    __shared__ int sSlot[CHUNK];

    for (int br = 0; br < 2; ++br){
        if (BUILD){
            const float* att = br ? att_sig : att_mu;
            const float* bas = br ? basis_sig : basis_mu;
            float a[NB];
            #pragma unroll
            for (int b = 0; b < NB; ++b) a[b] = att[t*NB + b];
            for (int pos = threadIdx.x; pos < DIN*DOUT; pos += 256){
                float w = 0.f;
                #pragma unroll
                for (int b = 0; b < NB; ++b) w += a[b] * bas[b*DIN*DOUT + pos];
                sW[pos] = f32_to_bf16(w);
            }
        } else {
            const uint4* g = (const uint4*)((br ? Wsig : Wmu) + (size_t)t * (DIN*DOUT));
            uint4* s = (uint4*)sW;
            for (int q = threadIdx.x; q < (DIN*DOUT*2)/16; q += 256) s[q] = g[q];
        }
        __syncthreads();
        float* agg = br ? agg_sig : agg_mu;

        for (int c0 = start; c0 < end; c0 += CHUNK){
            int kc = min(CHUNK, end - c0);
            if (threadIdx.x < kc){
                int e = sorted_e[c0 + threadIdx.x];
                sSlot[threadIdx.x] = ovr[eidx[E2V + e]];
            }
            for (int q = threadIdx.x; q < kc*DIN; q += 256){
                int eL = q / DIN, i = q - eL*DIN;
                int e = sorted_e[c0 + eL];
                float v;
                if (i < 100){
                    int s_ = eidx[e];
                    int p = ovr[s_];
                    v = (p >= 0) ? unseen_emb[(size_t)p*100 + i]
                                 : ent[(size_t)node_id[s_]*100 + i];
                } else {
                    v = rel_table[(size_t)rel_index[e]*100 + (i - 100)];
                }
                sM[eL][i] = v;
            }
            __syncthreads();
            for (int q = threadIdx.x; q < kc*DOUT; q += 256){
                int eL = q / DOUT, j = q - eL*DOUT;
                float acc = 0.f;
                #pragma unroll 4
                for (int i = 0; i < DIN; ++i)
                    acc += sM[eL][i] * bf16_to_f32(sW[i*DOUT + j]);
                atomicAdd(&agg[(size_t)sSlot[eL]*DOUT + j], acc);
            }
            __syncthreads();
        }
        __syncthreads();
    }
}

// ---- K8: out = agg/max(cnt,1) + x@root + bias, for the 500 output rows ----
__global__ void k_final(const int* __restrict__ unseen_index, const int* __restrict__ ovr,
                        const int* __restrict__ cnt,
                        const float* __restrict__ agg_mu, const float* __restrict__ agg_sig,
                        const float* __restrict__ unseen_emb,
                        const float* __restrict__ root_mu, const float* __restrict__ root_sig,
                        const float* __restrict__ bias_mu, const float* __restrict__ bias_sig,
                        float* __restrict__ out){
    int u = blockIdx.x;
    int n = unseen_index[u];
    int slot = ovr[n];                 // canonical (last) position; >=0 always
    __shared__ float sX[100];
    if (threadIdx.x < 100) sX[threadIdx.x] = unseen_emb[(size_t)slot*100 + threadIdx.x];
    __syncthreads();
    float inv = 1.f / fmaxf((float)cnt[slot], 1.f);
    int tid = threadIdx.x;
    if (tid < 100){
        int j = tid;
        float acc = bias_mu[j];
        for (int i = 0; i < 100; ++i) acc += sX[i] * root_mu[i*100 + j];
        float v = agg_mu[(size_t)slot*100 + j] * inv + acc;
        out[(size_t)u*100 + j] = v;
        out[(size_t)UCNT*100 + (size_t)u*100 + j] = v;
    } else if (tid >= 128 && tid < 228){
        int j = tid - 128;
        float acc = bias_sig[j];
        for (int i = 0; i < 100; ++i) acc += sX[i] * root_sig[i*100 + j];
        out[(size_t)2*UCNT*100 + (size_t)u*100 + j] =
            agg_sig[(size_t)slot*100 + j] * inv + acc;
    }
}

extern "C" void kernel_launch(void* const* d_in, const int* in_sizes, int n_in,
                              void* d_out, int out_size, void* d_ws, size_t ws_size,
                              hipStream_t stream){
    const float* ent        = (const float*)d_in[0];
    const float* rel_table  = (const float*)d_in[1];
    const float* unseen_emb = (const float*)d_in[2];
    const float* att_mu     = (const float*)d_in[3];
    const float* basis_mu   = (const float*)d_in[4];
    const float* root_mu    = (const float*)d_in[5];
    const float* bias_mu    = (const float*)d_in[6];
    const float* att_sig    = (const float*)d_in[7];
    const float* basis_sig  = (const float*)d_in[8];
    const float* root_sig   = (const float*)d_in[9];
    const float* bias_sig   = (const float*)d_in[10];
    const int* node_id      = (const int*)d_in[11];
    const int* edge_index   = (const int*)d_in[12];
    const int* edge_type    = (const int*)d_in[13];
    const int* rel_index    = (const int*)d_in[14];
    const int* unseen_index = (const int*)d_in[15];
    float* out = (float*)d_out;
    char* ws = (char*)d_ws;

    int*   ovr      = (int*)(ws + OFF_OVR);
    int*   tcnt     = (int*)(ws + OFF_TCNT);
    int*   tcur     = (int*)(ws + OFF_TCUR);
    int*   cnt      = (int*)(ws + OFF_CNT);
    int*   nfilt    = (int*)(ws + OFF_NF);
    float* agg_mu   = (float*)(ws + OFF_AGGM);
    float* agg_sig  = (float*)(ws + OFF_AGGS);
    int*   filtered = (int*)(ws + OFF_FILT);
    int*   sorted_e = (int*)(ws + OFF_SORT);
    int*   toff     = (int*)(ws + OFF_TOFF);
    unsigned short* Wmu  = (unsigned short*)(ws + OFF_WMU);
    unsigned short* Wsig = (unsigned short*)(ws + OFF_WSIG);

    bool big = (ws_size >= NEED_BIG);

    // init: override_pos = -1 (0xFF bytes), counters/agg = 0
    hipMemsetAsync(ws + OFF_OVR, 0xFF, (size_t)NNODES*4, stream);
    hipMemsetAsync(ws + ZERO_BEG, 0, ZERO_END - ZERO_BEG, stream);

    k_scatter<<<1, 512, 0, stream>>>(unseen_index, ovr);

    int gridE = (E2V + 255) / 256;
    k_filter<<<gridE, 256, 0, stream>>>(edge_index, edge_type, ovr,
                                        filtered, nfilt, tcnt, cnt);
    k_prefix<<<1, 512, 0, stream>>>(tcnt, toff);
    k_bin<<<gridE, 256, 0, stream>>>(filtered, nfilt, edge_type, toff, tcur, sorted_e);

    if (big){
        dim3 g((DIN*DOUT + 255)/256, 4);
        k_buildW<<<g, 256, 0, stream>>>(att_mu, att_sig, basis_mu, basis_sig, Wmu, Wsig);
        k_msg<false><<<NTYPE, 256, 0, stream>>>(toff, sorted_e, ovr, edge_index,
            rel_index, node_id, ent, unseen_emb, rel_table,
            att_mu, att_sig, basis_mu, basis_sig, Wmu, Wsig, agg_mu, agg_sig);
    } else {
        k_msg<true><<<NTYPE, 256, 0, stream>>>(toff, sorted_e, ovr, edge_index,
            rel_index, node_id, ent, unseen_emb, rel_table,
            att_mu, att_sig, basis_mu, basis_sig, Wmu, Wsig, agg_mu, agg_sig);
    }

    k_final<<<UCNT, 256, 0, stream>>>(unseen_index, ovr, cnt, agg_mu, agg_sig,
                                      unseen_emb, root_mu, root_sig, bias_mu, bias_sig, out);
}

// Round 2
// 103.491 us; speedup vs baseline: 2.4102x; 2.4102x over previous
//
#include <hip/hip_runtime.h>
#include <stdint.h>

#define E2V     600000
#define NNODES  50000
#define UCNT    500
#define NTYPE   400
#define DE      100
#define DIN     200
#define DOUT    100
#define NB      16
#define CAP     256
#define KP      232      // padded k stride (elements) in LDS

using short8 = __attribute__((ext_vector_type(8))) short;
using f32x4  = __attribute__((ext_vector_type(4))) float;

static constexpr size_t align256(size_t x){ return (x + 255) & ~size_t(255); }
static constexpr size_t OFF_OVR   = 0;                                     // 50000 i32, init -1
static constexpr size_t OFF_TCUR  = align256(OFF_OVR + (size_t)NNODES*4);  // 400 i32
static constexpr size_t OFF_CNT   = OFF_TCUR + NTYPE*4;                    // 500 i32
static constexpr size_t OFF_AGGM  = align256(OFF_CNT + UCNT*4);            // 500*100 f32
static constexpr size_t OFF_AGGS  = OFF_AGGM + (size_t)UCNT*DOUT*4;        // 500*100 f32
static constexpr size_t ZERO_BEG  = OFF_TCUR;
static constexpr size_t ZERO_END  = OFF_AGGS + (size_t)UCNT*DOUT*4;
static constexpr size_t OFF_ELIST = align256(ZERO_END);                    // 400*256 i32
static constexpr size_t OFF_BTM   = align256(OFF_ELIST + (size_t)NTYPE*CAP*4); // 16*100*200 f32
static constexpr size_t OFF_BTS   = OFF_BTM + (size_t)NB*DOUT*DIN*4;
static constexpr size_t NEED_SMALL= OFF_BTS + (size_t)NB*DOUT*DIN*4;       // ~5.0 MB
static constexpr size_t OFF_WTM   = align256(NEED_SMALL);                  // 400*100*200 bf16
static constexpr size_t OFF_WTS   = OFF_WTM + (size_t)NTYPE*DOUT*DIN*2;
static constexpr size_t NEED_BIG  = OFF_WTS + (size_t)NTYPE*DOUT*DIN*2;    // ~37 MB

__device__ __forceinline__ unsigned short f2b(float f){
    uint32_t u = __float_as_uint(f);
    uint32_t r = (u + 0x7FFFu + ((u >> 16) & 1u)) >> 16;
    return (unsigned short)r;
}

// ---- scatter unseen positions (last-wins via atomicMax) ----
__global__ void k_scatter(const int* __restrict__ unseen_index, int* __restrict__ ovr){
    int u = threadIdx.x + blockIdx.x * blockDim.x;
    if (u < UCNT) atomicMax(&ovr[unseen_index[u]], u);
}

// ---- single-pass: filter edges with unseen dst, append to per-type list, count per slot ----
__global__ void k_filter(const int* __restrict__ eidx, const int* __restrict__ etype,
                         const int* __restrict__ ovr,
                         int* __restrict__ tcur, int* __restrict__ cnt,
                         int* __restrict__ elist){
    int e = threadIdx.x + blockIdx.x * 256;
    if (e >= E2V) return;
    int slot = ovr[eidx[E2V + e]];
    if (slot >= 0){
        int t = etype[e];
        int pos = atomicAdd(&tcur[t], 1);
        if (pos < CAP) elist[t * CAP + pos] = e;
        atomicAdd(&cnt[slot], 1);
    }
}

// ---- transpose basis [b][k][j] -> basisT [b][j][k], both branches ----
__global__ void k_transpose(const float* __restrict__ bm, const float* __restrict__ bs,
                            float* __restrict__ btm, float* __restrict__ bts){
    __shared__ float tile[32][33];
    int b  = blockIdx.z & 15, br = blockIdx.z >> 4;
    const float* src = br ? bs : bm;
    float* dst = br ? bts : btm;
    int k0 = blockIdx.x * 32, j0 = blockIdx.y * 32;
    int tx = threadIdx.x & 31, ty = threadIdx.x >> 5;   // 8 rows per pass
    for (int r = ty; r < 32; r += 8){
        int k = k0 + r, j = j0 + tx;
        if (k < DIN && j < DOUT)
            tile[r][tx] = src[(size_t)b*DIN*DOUT + (size_t)k*DOUT + j];
    }
    __syncthreads();
    for (int r = ty; r < 32; r += 8){
        int j = j0 + r, k = k0 + tx;
        if (j < DOUT && k < DIN)
            dst[(size_t)b*DOUT*DIN + (size_t)j*DIN + k] = tile[tx][r];
    }
}

// ---- build Wt[t][j][k] = sum_b att[t][b]*basisT[b][j][k], bf16, coalesced ----
__global__ __launch_bounds__(256) void k_buildWt(
        const float* __restrict__ am, const float* __restrict__ as_,
        const float* __restrict__ btm, const float* __restrict__ bts,
        unsigned short* __restrict__ wtm, unsigned short* __restrict__ wts){
    int jk = blockIdx.x * 256 + threadIdx.x;       // float4 index over 100*200/4 = 5000
    if (jk >= DOUT*DIN/4) return;
    int t0 = blockIdx.y * 50;
    float bmv[NB][4], bsv[NB][4];
    #pragma unroll
    for (int b = 0; b < NB; ++b){
        const float4 vm = *(const float4*)&btm[(size_t)b*DOUT*DIN + (size_t)jk*4];
        const float4 vs = *(const float4*)&bts[(size_t)b*DOUT*DIN + (size_t)jk*4];
        bmv[b][0]=vm.x; bmv[b][1]=vm.y; bmv[b][2]=vm.z; bmv[b][3]=vm.w;
        bsv[b][0]=vs.x; bsv[b][1]=vs.y; bsv[b][2]=vs.z; bsv[b][3]=vs.w;
    }
    for (int tl = 0; tl < 50; ++tl){
        int t = t0 + tl;
        float wm[4] = {0,0,0,0}, ws[4] = {0,0,0,0};
        #pragma unroll
        for (int b = 0; b < NB; ++b){
            float a = am[t*NB + b], s = as_[t*NB + b];
            #pragma unroll
            for (int q = 0; q < 4; ++q){ wm[q] += a*bmv[b][q]; ws[q] += s*bsv[b][q]; }
        }
        ushort4 om, os;
        om.x=f2b(wm[0]); om.y=f2b(wm[1]); om.z=f2b(wm[2]); om.w=f2b(wm[3]);
        os.x=f2b(ws[0]); os.y=f2b(ws[1]); os.z=f2b(ws[2]); os.w=f2b(ws[3]);
        *(ushort4*)&wtm[(size_t)t*DOUT*DIN + (size_t)jk*4] = om;
        *(ushort4*)&wts[(size_t)t*DOUT*DIN + (size_t)jk*4] = os;
    }
}

// ---- per-type MFMA messages -> atomic agg ----
template<bool BUILD>
__global__ __launch_bounds__(256) void k_msg(
        const int* __restrict__ tcur, const int* __restrict__ elist,
        const int* __restrict__ ovr, const int* __restrict__ eidx,
        const int* __restrict__ rel_index, const int* __restrict__ node_id,
        const float* __restrict__ ent, const float* __restrict__ unseen,
        const float* __restrict__ rel,
        const float* __restrict__ am, const float* __restrict__ as_,
        const float* __restrict__ btm, const float* __restrict__ bts,
        const unsigned short* __restrict__ wtm, const unsigned short* __restrict__ wts,
        float* __restrict__ aggm, float* __restrict__ aggs){
    int t = blockIdx.x;
    int nE = tcur[t]; if (nE > CAP) nE = CAP;
    if (nE == 0) return;
    __shared__ unsigned short sWt[100 * KP];   // W^T: [j][k], bf16
    __shared__ unsigned short sMb[32 * KP];    // m:   [edge][k], bf16
    __shared__ int sSlot[32];
    __shared__ const float* sPtrX[32];
    __shared__ const float* sPtrR[32];
    int tid = threadIdx.x;

    // zero both buffers once (pads must be 0; staging only writes k<200)
    for (int q = tid; q < (100*KP)/2; q += 256) ((uint32_t*)sWt)[q] = 0;
    for (int q = tid; q < (32*KP)/2;  q += 256) ((uint32_t*)sMb)[q] = 0;
    __syncthreads();

    for (int c0 = 0; c0 < nE; c0 += 32){
        int kc = nE - c0; if (kc > 32) kc = 32;
        // resolve edge pointers + slots
        if (tid < 32){
            if (tid < kc){
                int e = elist[t*CAP + c0 + tid];
                sSlot[tid] = ovr[eidx[E2V + e]];
                int s = eidx[e];
                int p = ovr[s];
                sPtrX[tid] = (p >= 0) ? unseen + (size_t)p*DE
                                      : ent + (size_t)node_id[s]*DE;
                sPtrR[tid] = rel + (size_t)rel_index[e]*DE;
            } else sSlot[tid] = -1;
        }
        __syncthreads();
        // stage m -> bf16 LDS (shared by both branches)
        for (int q = tid; q < kc*50; q += 256){
            int eL = q / 50, s = q % 50;
            const float* base = (s < 25) ? sPtrX[eL] : sPtrR[eL];
            int off = (s < 25) ? s*4 : (s-25)*4;
            float4 v = *(const float4*)(base + off);
            int kb = (s < 25) ? s*4 : (s-25)*4 + 100;
            ushort4 o; o.x=f2b(v.x); o.y=f2b(v.y); o.z=f2b(v.z); o.w=f2b(v.w);
            *(ushort4*)&sMb[eL*KP + kb] = o;
        }
        for (int br = 0; br < 2; ++br){
            // stage W^T for this branch
            if (!BUILD){
                const uint4* g = (const uint4*)((br ? wts : wtm) + (size_t)t*DOUT*DIN);
                for (int q = tid; q < DOUT*DIN/8; q += 256){     // 2500 x 16B
                    int row = q / 25, c = q % 25;
                    *(uint4*)&sWt[row*KP + c*8] = g[q];
                }
            } else {
                const float* att = br ? as_ : am;
                const float* bt  = br ? bts : btm;
                float a[NB];
                #pragma unroll
                for (int b = 0; b < NB; ++b) a[b] = att[t*NB + b];
                for (int q = tid; q < DOUT*DIN/4; q += 256){     // 5000 float4 positions
                    int j = q / 50, kv = q % 50;
                    float w0=0,w1=0,w2=0,w3=0;
                    #pragma unroll
                    for (int b = 0; b < NB; ++b){
                        float4 bv = *(const float4*)&bt[(size_t)b*DOUT*DIN + (size_t)q*4];
                        w0 += a[b]*bv.x; w1 += a[b]*bv.y; w2 += a[b]*bv.z; w3 += a[b]*bv.w;
                    }
                    ushort4 o; o.x=f2b(w0); o.y=f2b(w1); o.z=f2b(w2); o.w=f2b(w3);
                    *(ushort4*)&sWt[j*KP + kv*4] = o;
                }
            }
            __syncthreads();
            // MFMA: C[32 edges x 100 j] = M @ W
            float* agg = br ? aggs : aggm;
            int wv = tid >> 6, lane = tid & 63;
            int rowa = lane & 15, ko = (lane >> 4) * 8;
            for (int jt = wv; jt < 7; jt += 4){
                int j0 = (jt == 6) ? 84 : jt*16;     // last tile overlaps; guard col>=96
                const unsigned short* bp = &sWt[(j0 + rowa)*KP + ko];
                int col = j0 + rowa;
                for (int et = 0; et*16 < kc; ++et){
                    const unsigned short* ap = &sMb[(et*16 + rowa)*KP + ko];
                    f32x4 acc = {0.f, 0.f, 0.f, 0.f};
                    #pragma unroll
                    for (int ks = 0; ks < 7; ++ks){
                        short8 av = *(const short8*)(ap + ks*32);
                        short8 bv = *(const short8*)(bp + ks*32);
                        acc = __builtin_amdgcn_mfma_f32_16x16x32_bf16(av, bv, acc, 0, 0, 0);
                    }
                    if (jt < 6 || col >= 96){
                        int r0 = et*16 + (lane >> 4)*4;
                        #pragma unroll
                        for (int r = 0; r < 4; ++r){
                            int sl = sSlot[r0 + r];
                            if (sl >= 0) atomicAdd(&agg[(size_t)sl*DOUT + col], acc[r]);
                        }
                    }
                }
            }
            __syncthreads();
        }
    }
}

// ---- out = agg/max(cnt,1) + x@root + bias for the 500 output rows ----
__global__ void k_final(const int* __restrict__ unseen_index, const int* __restrict__ ovr,
                        const int* __restrict__ cnt,
                        const float* __restrict__ agg_mu, const float* __restrict__ agg_sig,
                        const float* __restrict__ unseen_emb,
                        const float* __restrict__ root_mu, const float* __restrict__ root_sig,
                        const float* __restrict__ bias_mu, const float* __restrict__ bias_sig,
                        float* __restrict__ out){
    int u = blockIdx.x;
    int n = unseen_index[u];
    int slot = ovr[n];
    __shared__ float sX[100];
    if (threadIdx.x < 100) sX[threadIdx.x] = unseen_emb[(size_t)slot*100 + threadIdx.x];
    __syncthreads();
    float inv = 1.f / fmaxf((float)cnt[slot], 1.f);
    int tid = threadIdx.x;
    if (tid < 100){
        int j = tid;
        float acc = bias_mu[j];
        for (int i = 0; i < 100; ++i) acc += sX[i] * root_mu[i*100 + j];
        float v = agg_mu[(size_t)slot*100 + j] * inv + acc;
        out[(size_t)u*100 + j] = v;
        out[(size_t)UCNT*100 + (size_t)u*100 + j] = v;
    } else if (tid >= 128 && tid < 228){
        int j = tid - 128;
        float acc = bias_sig[j];
        for (int i = 0; i < 100; ++i) acc += sX[i] * root_sig[i*100 + j];
        out[(size_t)2*UCNT*100 + (size_t)u*100 + j] =
            agg_sig[(size_t)slot*100 + j] * inv + acc;
    }
}

extern "C" void kernel_launch(void* const* d_in, const int* in_sizes, int n_in,
                              void* d_out, int out_size, void* d_ws, size_t ws_size,
                              hipStream_t stream){
    const float* ent        = (const float*)d_in[0];
    const float* rel_table  = (const float*)d_in[1];
    const float* unseen_emb = (const float*)d_in[2];
    const float* att_mu     = (const float*)d_in[3];
    const float* basis_mu   = (const float*)d_in[4];
    const float* root_mu    = (const float*)d_in[5];
    const float* bias_mu    = (const float*)d_in[6];
    const float* att_sig    = (const float*)d_in[7];
    const float* basis_sig  = (const float*)d_in[8];
    const float* root_sig   = (const float*)d_in[9];
    const float* bias_sig   = (const float*)d_in[10];
    const int* node_id      = (const int*)d_in[11];
    const int* edge_index   = (const int*)d_in[12];
    const int* edge_type    = (const int*)d_in[13];
    const int* rel_index    = (const int*)d_in[14];
    const int* unseen_index = (const int*)d_in[15];
    float* out = (float*)d_out;
    char* ws = (char*)d_ws;

    int* ovr     = (int*)(ws + OFF_OVR);
    int* tcur    = (int*)(ws + OFF_TCUR);
    int* cnt     = (int*)(ws + OFF_CNT);
    float* aggm  = (float*)(ws + OFF_AGGM);
    float* aggs  = (float*)(ws + OFF_AGGS);
    int* elist   = (int*)(ws + OFF_ELIST);
    float* btm   = (float*)(ws + OFF_BTM);
    float* bts   = (float*)(ws + OFF_BTS);
    unsigned short* wtm = (unsigned short*)(ws + OFF_WTM);
    unsigned short* wts = (unsigned short*)(ws + OFF_WTS);

    bool big = (ws_size >= NEED_BIG);

    hipMemsetAsync(ws + OFF_OVR, 0xFF, (size_t)NNODES*4, stream);
    hipMemsetAsync(ws + ZERO_BEG, 0, ZERO_END - ZERO_BEG, stream);

    k_scatter<<<1, 512, 0, stream>>>(unseen_index, ovr);
    k_filter<<<(E2V + 255)/256, 256, 0, stream>>>(edge_index, edge_type, ovr,
                                                  tcur, cnt, elist);
    k_transpose<<<dim3(7,4,32), 256, 0, stream>>>(basis_mu, basis_sig, btm, bts);

    if (big){
        k_buildWt<<<dim3(20,8), 256, 0, stream>>>(att_mu, att_sig, btm, bts, wtm, wts);
        k_msg<false><<<NTYPE, 256, 0, stream>>>(tcur, elist, ovr, edge_index,
            rel_index, node_id, ent, unseen_emb, rel_table,
            att_mu, att_sig, btm, bts, wtm, wts, aggm, aggs);
    } else {
        k_msg<true><<<NTYPE, 256, 0, stream>>>(tcur, elist, ovr, edge_index,
            rel_index, node_id, ent, unseen_emb, rel_table,
            att_mu, att_sig, btm, bts, wtm, wts, aggm, aggs);
    }

    k_final<<<UCNT, 256, 0, stream>>>(unseen_index, ovr, cnt, aggm, aggs,
                                      unseen_emb, root_mu, root_sig, bias_mu, bias_sig, out);
}

// Round 3
// 61.346 us; speedup vs baseline: 4.0659x; 1.6870x over previous
//
#include <hip/hip_runtime.h>
#include <stdint.h>

#define E2V     600000
#define NNODES  50000
#define UCNT    500
#define NTYPE   400
#define DE      100
#define DIN     200
#define DOUT    100
#define NB      16
#define CAP     256
#define KP      232      // padded k stride (elements) in LDS

#define FILT_BLOCKS ((E2V + 255) / 256)          // 2344
#define BW_BLOCKS   (20 * 50 * 2)                // 2000

using short8 = __attribute__((ext_vector_type(8))) short;
using f32x4  = __attribute__((ext_vector_type(4))) float;

static constexpr size_t align256(size_t x){ return (x + 255) & ~size_t(255); }
static constexpr size_t OFF_OVR   = 0;                                     // 50000 i32, init -1
static constexpr size_t OFF_TCUR  = align256(OFF_OVR + (size_t)NNODES*4);  // 400 i32
static constexpr size_t OFF_CNT   = OFF_TCUR + NTYPE*4;                    // 500 i32
static constexpr size_t OFF_AGGM  = align256(OFF_CNT + UCNT*4);            // 500*100 f32
static constexpr size_t OFF_AGGS  = OFF_AGGM + (size_t)UCNT*DOUT*4;        // 500*100 f32
static constexpr size_t ZERO_BEG  = OFF_TCUR;
static constexpr size_t ZERO_END  = OFF_AGGS + (size_t)UCNT*DOUT*4;
static constexpr int    NZ        = (int)((ZERO_END - ZERO_BEG) / 4);
static constexpr size_t OFF_ELIST = align256(ZERO_END);                    // 400*256 i32
static constexpr size_t OFF_BTM   = align256(OFF_ELIST + (size_t)NTYPE*CAP*4); // 16*100*200 f32
static constexpr size_t OFF_BTS   = OFF_BTM + (size_t)NB*DOUT*DIN*4;
static constexpr size_t NEED_SMALL= OFF_BTS + (size_t)NB*DOUT*DIN*4;       // ~5.0 MB
static constexpr size_t OFF_WTM   = align256(NEED_SMALL);                  // 400*100*200 bf16
static constexpr size_t OFF_WTS   = OFF_WTM + (size_t)NTYPE*DOUT*DIN*2;
static constexpr size_t NEED_BIG  = OFF_WTS + (size_t)NTYPE*DOUT*DIN*2;    // ~37 MB

__device__ __forceinline__ unsigned short f2b(float f){
    uint32_t u = __float_as_uint(f);
    uint32_t r = (u + 0x7FFFu + ((u >> 16) & 1u)) >> 16;
    return (unsigned short)r;
}

// ---- init: ovr = -1, counters/agg = 0 (replaces two memsets) ----
__global__ void k_init(int* __restrict__ ovr, uint32_t* __restrict__ z){
    int i = threadIdx.x + blockIdx.x * 256;
    if (i < NNODES) ovr[i] = -1;
    if (i < NZ) z[i] = 0;
}

// ---- fused: scatter unseen positions (block 896) + basis transpose (blocks 0..895) ----
__global__ __launch_bounds__(256) void k_pre(
        const int* __restrict__ unseen_index, int* __restrict__ ovr,
        const float* __restrict__ bm, const float* __restrict__ bs,
        float* __restrict__ btm, float* __restrict__ bts){
    int bx = blockIdx.x;
    if (bx == 896){
        for (int u = threadIdx.x; u < UCNT; u += 256)
            atomicMax(&ovr[unseen_index[u]], u);
        return;
    }
    __shared__ float tile[32][33];
    int k0 = (bx % 7) * 32;
    int j0 = ((bx / 7) % 4) * 32;
    int zz = bx / 28;                      // 0..31
    int b  = zz & 15, br = zz >> 4;
    const float* src = br ? bs : bm;
    float* dst = br ? bts : btm;
    int tx = threadIdx.x & 31, ty = threadIdx.x >> 5;
    for (int r = ty; r < 32; r += 8){
        int k = k0 + r, j = j0 + tx;
        if (k < DIN && j < DOUT)
            tile[r][tx] = src[(size_t)b*DIN*DOUT + (size_t)k*DOUT + j];
    }
    __syncthreads();
    for (int r = ty; r < 32; r += 8){
        int j = j0 + r, k = k0 + tx;
        if (j < DOUT && k < DIN)
            dst[(size_t)b*DOUT*DIN + (size_t)j*DIN + k] = tile[tx][r];
    }
}

// ---- fused: edge filter (blocks < FILT_BLOCKS) + buildWt (rest, BIG only) ----
template<bool BIG>
__global__ __launch_bounds__(256) void k_mid(
        const int* __restrict__ eidx, const int* __restrict__ etype,
        const int* __restrict__ ovr,
        int* __restrict__ tcur, int* __restrict__ cnt, int* __restrict__ elist,
        const float* __restrict__ am, const float* __restrict__ as_,
        const float* __restrict__ btm, const float* __restrict__ bts,
        unsigned short* __restrict__ wtm, unsigned short* __restrict__ wts){
    int bx = blockIdx.x;
    if (bx < FILT_BLOCKS){
        int e = threadIdx.x + bx * 256;
        if (e >= E2V) return;
        int slot = ovr[eidx[E2V + e]];
        if (slot >= 0){
            int t = etype[e];
            int pos = atomicAdd(&tcur[t], 1);
            if (pos < CAP) elist[t * CAP + pos] = e;
            atomicAdd(&cnt[slot], 1);
        }
        return;
    }
    if (!BIG) return;
    int id = bx - FILT_BLOCKS;
    int jb = id % 20;
    int tb = (id / 20) % 50;
    int br = id / 1000;
    int jk = jb * 256 + threadIdx.x;       // float4 index over 100*200/4 = 5000
    bool act = jk < DOUT*DIN/4;
    const float* att = br ? as_ : am;
    const float* bt  = br ? bts : btm;
    unsigned short* wt = br ? wts : wtm;
    float bv[NB][4];
    if (act){
        #pragma unroll
        for (int b = 0; b < NB; ++b){
            float4 v = *(const float4*)&bt[(size_t)b*DOUT*DIN + (size_t)jk*4];
            bv[b][0]=v.x; bv[b][1]=v.y; bv[b][2]=v.z; bv[b][3]=v.w;
        }
    }
    int t0 = tb * 8;
    #pragma unroll
    for (int tl = 0; tl < 8; ++tl){
        int t = t0 + tl;
        float w0=0,w1=0,w2=0,w3=0;
        #pragma unroll
        for (int b = 0; b < NB; ++b){
            float a = att[t*NB + b];       // block-uniform -> s_load
            w0 += a*bv[b][0]; w1 += a*bv[b][1]; w2 += a*bv[b][2]; w3 += a*bv[b][3];
        }
        if (act){
            ushort4 o; o.x=f2b(w0); o.y=f2b(w1); o.z=f2b(w2); o.w=f2b(w3);
            *(ushort4*)&wt[(size_t)t*DOUT*DIN + (size_t)jk*4] = o;
        }
    }
}

// ---- per-type MFMA messages -> atomic agg ----
template<bool BUILD>
__global__ __launch_bounds__(256) void k_msg(
        const int* __restrict__ tcur, const int* __restrict__ elist,
        const int* __restrict__ ovr, const int* __restrict__ eidx,
        const int* __restrict__ rel_index, const int* __restrict__ node_id,
        const float* __restrict__ ent, const float* __restrict__ unseen,
        const float* __restrict__ rel,
        const float* __restrict__ am, const float* __restrict__ as_,
        const float* __restrict__ btm, const float* __restrict__ bts,
        const unsigned short* __restrict__ wtm, const unsigned short* __restrict__ wts,
        float* __restrict__ aggm, float* __restrict__ aggs){
    int t = blockIdx.x;
    int nE = tcur[t]; if (nE > CAP) nE = CAP;
    if (nE == 0) return;
    __shared__ unsigned short sWt[100 * KP];   // W^T: [j][k], bf16
    __shared__ unsigned short sMb[32 * KP];    // m:   [edge][k], bf16
    __shared__ int sSlot[32];
    __shared__ const float* sPtrX[32];
    __shared__ const float* sPtrR[32];
    int tid = threadIdx.x;

    for (int q = tid; q < (100*KP)/2; q += 256) ((uint32_t*)sWt)[q] = 0;
    for (int q = tid; q < (32*KP)/2;  q += 256) ((uint32_t*)sMb)[q] = 0;
    __syncthreads();

    for (int c0 = 0; c0 < nE; c0 += 32){
        int kc = nE - c0; if (kc > 32) kc = 32;
        if (tid < 32){
            if (tid < kc){
                int e = elist[t*CAP + c0 + tid];
                sSlot[tid] = ovr[eidx[E2V + e]];
                int s = eidx[e];
                int p = ovr[s];
                sPtrX[tid] = (p >= 0) ? unseen + (size_t)p*DE
                                      : ent + (size_t)node_id[s]*DE;
                sPtrR[tid] = rel + (size_t)rel_index[e]*DE;
            } else sSlot[tid] = -1;
        }
        __syncthreads();
        for (int q = tid; q < kc*50; q += 256){
            int eL = q / 50, s = q % 50;
            const float* base = (s < 25) ? sPtrX[eL] : sPtrR[eL];
            int off = (s < 25) ? s*4 : (s-25)*4;
            float4 v = *(const float4*)(base + off);
            int kb = (s < 25) ? s*4 : (s-25)*4 + 100;
            ushort4 o; o.x=f2b(v.x); o.y=f2b(v.y); o.z=f2b(v.z); o.w=f2b(v.w);
            *(ushort4*)&sMb[eL*KP + kb] = o;
        }
        for (int br = 0; br < 2; ++br){
            if (!BUILD){
                const uint4* g = (const uint4*)((br ? wts : wtm) + (size_t)t*DOUT*DIN);
                for (int q = tid; q < DOUT*DIN/8; q += 256){
                    int row = q / 25, c = q % 25;
                    *(uint4*)&sWt[row*KP + c*8] = g[q];
                }
            } else {
                const float* att = br ? as_ : am;
                const float* bt  = br ? bts : btm;
                float a[NB];
                #pragma unroll
                for (int b = 0; b < NB; ++b) a[b] = att[t*NB + b];
                for (int q = tid; q < DOUT*DIN/4; q += 256){
                    int j = q / 50, kv = q % 50;
                    float w0=0,w1=0,w2=0,w3=0;
                    #pragma unroll
                    for (int b = 0; b < NB; ++b){
                        float4 bv = *(const float4*)&bt[(size_t)b*DOUT*DIN + (size_t)q*4];
                        w0 += a[b]*bv.x; w1 += a[b]*bv.y; w2 += a[b]*bv.z; w3 += a[b]*bv.w;
                    }
                    ushort4 o; o.x=f2b(w0); o.y=f2b(w1); o.z=f2b(w2); o.w=f2b(w3);
                    *(ushort4*)&sWt[j*KP + kv*4] = o;
                }
            }
            __syncthreads();
            float* agg = br ? aggs : aggm;
            int wv = tid >> 6, lane = tid & 63;
            int rowa = lane & 15, ko = (lane >> 4) * 8;
            for (int jt = wv; jt < 7; jt += 4){
                int j0 = (jt == 6) ? 84 : jt*16;     // last tile overlaps; guard col>=96
                const unsigned short* bp = &sWt[(j0 + rowa)*KP + ko];
                int col = j0 + rowa;
                for (int et = 0; et*16 < kc; ++et){
                    const unsigned short* ap = &sMb[(et*16 + rowa)*KP + ko];
                    f32x4 acc = {0.f, 0.f, 0.f, 0.f};
                    #pragma unroll
                    for (int ks = 0; ks < 7; ++ks){
                        short8 av = *(const short8*)(ap + ks*32);
                        short8 bv = *(const short8*)(bp + ks*32);
                        acc = __builtin_amdgcn_mfma_f32_16x16x32_bf16(av, bv, acc, 0, 0, 0);
                    }
                    if (jt < 6 || col >= 96){
                        int r0 = et*16 + (lane >> 4)*4;
                        #pragma unroll
                        for (int r = 0; r < 4; ++r){
                            int sl = sSlot[r0 + r];
                            if (sl >= 0) atomicAdd(&agg[(size_t)sl*DOUT + col], acc[r]);
                        }
                    }
                }
            }
            __syncthreads();
        }
    }
}

// ---- out = agg/max(cnt,1) + x@root + bias for the 500 output rows ----
__global__ void k_final(const int* __restrict__ unseen_index, const int* __restrict__ ovr,
                        const int* __restrict__ cnt,
                        const float* __restrict__ agg_mu, const float* __restrict__ agg_sig,
                        const float* __restrict__ unseen_emb,
                        const float* __restrict__ root_mu, const float* __restrict__ root_sig,
                        const float* __restrict__ bias_mu, const float* __restrict__ bias_sig,
                        float* __restrict__ out){
    int u = blockIdx.x;
    int n = unseen_index[u];
    int slot = ovr[n];
    __shared__ float sX[100];
    if (threadIdx.x < 100) sX[threadIdx.x] = unseen_emb[(size_t)slot*100 + threadIdx.x];
    __syncthreads();
    float inv = 1.f / fmaxf((float)cnt[slot], 1.f);
    int tid = threadIdx.x;
    if (tid < 100){
        int j = tid;
        float acc = bias_mu[j];
        for (int i = 0; i < 100; ++i) acc += sX[i] * root_mu[i*100 + j];
        float v = agg_mu[(size_t)slot*100 + j] * inv + acc;
        out[(size_t)u*100 + j] = v;
        out[(size_t)UCNT*100 + (size_t)u*100 + j] = v;
    } else if (tid >= 128 && tid < 228){
        int j = tid - 128;
        float acc = bias_sig[j];
        for (int i = 0; i < 100; ++i) acc += sX[i] * root_sig[i*100 + j];
        out[(size_t)2*UCNT*100 + (size_t)u*100 + j] =
            agg_sig[(size_t)slot*100 + j] * inv + acc;
    }
}

extern "C" void kernel_launch(void* const* d_in, const int* in_sizes, int n_in,
                              void* d_out, int out_size, void* d_ws, size_t ws_size,
                              hipStream_t stream){
    const float* ent        = (const float*)d_in[0];
    const float* rel_table  = (const float*)d_in[1];
    const float* unseen_emb = (const float*)d_in[2];
    const float* att_mu     = (const float*)d_in[3];
    const float* basis_mu   = (const float*)d_in[4];
    const float* root_mu    = (const float*)d_in[5];
    const float* bias_mu    = (const float*)d_in[6];
    const float* att_sig    = (const float*)d_in[7];
    const float* basis_sig  = (const float*)d_in[8];
    const float* root_sig   = (const float*)d_in[9];
    const float* bias_sig   = (const float*)d_in[10];
    const int* node_id      = (const int*)d_in[11];
    const int* edge_index   = (const int*)d_in[12];
    const int* edge_type    = (const int*)d_in[13];
    const int* rel_index    = (const int*)d_in[14];
    const int* unseen_index = (const int*)d_in[15];
    float* out = (float*)d_out;
    char* ws = (char*)d_ws;

    int* ovr     = (int*)(ws + OFF_OVR);
    int* tcur    = (int*)(ws + OFF_TCUR);
    int* cnt     = (int*)(ws + OFF_CNT);
    float* aggm  = (float*)(ws + OFF_AGGM);
    float* aggs  = (float*)(ws + OFF_AGGS);
    int* elist   = (int*)(ws + OFF_ELIST);
    float* btm   = (float*)(ws + OFF_BTM);
    float* bts   = (float*)(ws + OFF_BTS);
    unsigned short* wtm = (unsigned short*)(ws + OFF_WTM);
    unsigned short* wts = (unsigned short*)(ws + OFF_WTS);

    bool big = (ws_size >= NEED_BIG);

    int initN = (NZ > NNODES ? NZ : NNODES);
    k_init<<<(initN + 255)/256, 256, 0, stream>>>(ovr, (uint32_t*)(ws + ZERO_BEG));
    k_pre<<<897, 256, 0, stream>>>(unseen_index, ovr, basis_mu, basis_sig, btm, bts);

    if (big){
        k_mid<true><<<FILT_BLOCKS + BW_BLOCKS, 256, 0, stream>>>(
            edge_index, edge_type, ovr, tcur, cnt, elist,
            att_mu, att_sig, btm, bts, wtm, wts);
        k_msg<false><<<NTYPE, 256, 0, stream>>>(tcur, elist, ovr, edge_index,
            rel_index, node_id, ent, unseen_emb, rel_table,
            att_mu, att_sig, btm, bts, wtm, wts, aggm, aggs);
    } else {
        k_mid<false><<<FILT_BLOCKS, 256, 0, stream>>>(
            edge_index, edge_type, ovr, tcur, cnt, elist,
            att_mu, att_sig, btm, bts, wtm, wts);
        k_msg<true><<<NTYPE, 256, 0, stream>>>(tcur, elist, ovr, edge_index,
            rel_index, node_id, ent, unseen_emb, rel_table,
            att_mu, att_sig, btm, bts, wtm, wts, aggm, aggs);
    }

    k_final<<<UCNT, 256, 0, stream>>>(unseen_index, ovr, cnt, aggm, aggs,
                                      unseen_emb, root_mu, root_sig, bias_mu, bias_sig, out);
}

// Round 4
// 59.195 us; speedup vs baseline: 4.2136x; 1.0363x over previous
//
#include <hip/hip_runtime.h>
#include <stdint.h>

#define E2V     600000
#define NNODES  50000
#define UCNT    500
#define DE      100
#define DOUT    100
#define NB      16
#define KTOT    3328      // 3200 (G) + 100 (x/root) + 1 (bias) + 27 pad
#define KCH     104       // KTOT/32
#define CAP2    128       // per-slot edge list capacity (expected ~12, max ~30)
#define MROWS   512       // padded slot rows

using short8 = __attribute__((ext_vector_type(8))) short;
using f32x4  = __attribute__((ext_vector_type(4))) float;

static constexpr size_t align256(size_t x){ return (x + 255) & ~size_t(255); }
static constexpr size_t OFF_OVR  = 0;                                        // 50000 i32
static constexpr size_t OFF_SCNT = align256(OFF_OVR + (size_t)NNODES*4);     // 512 i32
static constexpr size_t OFF_EL2  = align256(OFF_SCNT + 512*4);               // 512*128 i32
static constexpr size_t OFF_GM   = align256(OFF_EL2 + (size_t)512*CAP2*4);   // 512*3328 bf16
static constexpr size_t OFF_GS   = OFF_GM + (size_t)MROWS*KTOT*2;
static constexpr size_t OFF_BTM  = align256(OFF_GS + (size_t)MROWS*KTOT*2);  // 100*3328 bf16
static constexpr size_t OFF_BTS  = OFF_BTM + (size_t)DOUT*KTOT*2;
static constexpr size_t OFF_AGM  = align256(OFF_BTS + (size_t)DOUT*KTOT*2);  // 500*100 f32
static constexpr size_t OFF_AGS  = OFF_AGM + (size_t)UCNT*DOUT*4;            // total ~8.4 MB

#define TR_BLOCKS  (KCH * 4 * 2)     // 832: transpose basis/root/bias -> Bt
#define OVR_BLOCKS 196

__device__ __forceinline__ unsigned short f2b(float f){
    uint32_t u = __float_as_uint(f);
    uint32_t r = (u + 0x7FFFu + ((u >> 16) & 1u)) >> 16;
    return (unsigned short)r;
}

__device__ __forceinline__ float bt_src(const float* __restrict__ basis,
                                        const float* __restrict__ root,
                                        const float* __restrict__ bias,
                                        int k, int j){
    if (j >= 100) return 0.f;
    if (k < 3200) return basis[k*100 + j];
    if (k < 3300) return root[(k-3200)*100 + j];
    if (k == 3300) return bias[j];
    return 0.f;
}

// ---- K1: ovr=-1, scnt=0, and build B_aug^T (bf16 [j][k]) for both branches ----
__global__ __launch_bounds__(256) void k_init(
        int* __restrict__ ovr, int* __restrict__ scnt,
        const float* __restrict__ bm, const float* __restrict__ bs,
        const float* __restrict__ rm, const float* __restrict__ rs,
        const float* __restrict__ qm, const float* __restrict__ qs,
        unsigned short* __restrict__ btm, unsigned short* __restrict__ bts){
    int bx = blockIdx.x;
    if (bx >= TR_BLOCKS){
        int r = bx - TR_BLOCKS;
        if (r < OVR_BLOCKS){
            int i = r*256 + threadIdx.x;
            if (i < NNODES) ovr[i] = -1;
        } else {
            scnt[threadIdx.x] = 0; scnt[threadIdx.x + 256] = 0;
        }
        return;
    }
    int kt = bx % KCH, jt = (bx / KCH) & 3, br = bx / (KCH*4);
    const float* basis = br ? bs : bm;
    const float* root  = br ? rs : rm;
    const float* bias  = br ? qs : qm;
    unsigned short* bt = br ? bts : btm;
    int k0 = kt*32, j0 = jt*32;
    __shared__ float tile[32][33];
    int tx = threadIdx.x & 31, ty = threadIdx.x >> 5;
    for (int r = ty; r < 32; r += 8)
        tile[r][tx] = bt_src(basis, root, bias, k0 + r, j0 + tx);
    __syncthreads();
    for (int r = ty; r < 32; r += 8){
        int j = j0 + r;
        if (j < 100) bt[(size_t)j*KTOT + k0 + tx] = f2b(tile[tx][r]);
    }
}

// ---- K2: scatter unseen positions (last-wins via atomicMax) ----
__global__ void k_scatter(const int* __restrict__ unseen_index, int* __restrict__ ovr){
    int u = threadIdx.x;
    if (u < UCNT) atomicMax(&ovr[unseen_index[u]], u);
}

// ---- K3: filter edges with unseen dst -> per-slot lists ----
__global__ void k_filter(const int* __restrict__ eidx, const int* __restrict__ ovr,
                         int* __restrict__ scnt, int* __restrict__ elist){
    int e = threadIdx.x + blockIdx.x * 256;
    if (e >= E2V) return;
    int slot = ovr[eidx[E2V + e]];
    if (slot >= 0){
        int pos = atomicAdd(&scnt[slot], 1);
        if (pos < CAP2) elist[slot * CAP2 + pos] = e;
    }
}

// ---- K4: build G rows: G[slot] = [ (1/cnt)*sum_e att[t_e]⊗m_e | x | 1 | 0 ] bf16 ----
__global__ __launch_bounds__(256) void k_g(
        const int* __restrict__ scnt, const int* __restrict__ elist,
        const int* __restrict__ ovr, const int* __restrict__ eidx,
        const int* __restrict__ etype, const int* __restrict__ rel_index,
        const int* __restrict__ node_id,
        const float* __restrict__ ent, const float* __restrict__ unseen,
        const float* __restrict__ rel,
        const float* __restrict__ am, const float* __restrict__ as_,
        unsigned short* __restrict__ Gm, unsigned short* __restrict__ Gs){
    int slot = blockIdx.x;
    int tid  = threadIdx.x;
    int nE = (slot < UCNT) ? scnt[slot] : 0;
    if (nE > CAP2) nE = CAP2;
    __shared__ __align__(16) float sM[8][200];
    __shared__ __align__(16) float sAm[8][16], sAs[8][16];
    __shared__ const float* sPX[8];
    __shared__ const float* sPR[8];
    __shared__ int sT[8];
    float gm[16], gs[16];
    #pragma unroll
    for (int b = 0; b < NB; ++b){ gm[b] = 0.f; gs[b] = 0.f; }

    for (int c0 = 0; c0 < nE; c0 += 8){
        int kc = nE - c0; if (kc > 8) kc = 8;
        if (tid < kc){
            int e = elist[slot*CAP2 + c0 + tid];
            sT[tid] = etype[e];
            int s = eidx[e];
            int p = ovr[s];
            sPX[tid] = (p >= 0) ? unseen + (size_t)p*DE : ent + (size_t)node_id[s]*DE;
            sPR[tid] = rel + (size_t)rel_index[e]*DE;
        }
        __syncthreads();
        for (int q = tid; q < kc*50; q += 256){
            int eL = q / 50, s = q % 50;
            const float* base = (s < 25) ? sPX[eL] : sPR[eL];
            int off = (s < 25) ? s*4 : (s-25)*4;
            float4 v = *(const float4*)(base + off);
            int kb = (s < 25) ? s*4 : (s-25)*4 + 100;
            *(float4*)&sM[eL][kb] = v;
        }
        if (tid < kc*16){
            int eL = tid >> 4, b = tid & 15;
            int t = sT[eL];
            sAm[eL][b] = am[t*NB + b];
            sAs[eL][b] = as_[t*NB + b];
        }
        __syncthreads();
        if (tid < 200){
            for (int e = 0; e < kc; ++e){
                float mk = sM[e][tid];
                const float4* pa = (const float4*)&sAm[e][0];
                const float4* ps = (const float4*)&sAs[e][0];
                #pragma unroll
                for (int q = 0; q < 4; ++q){
                    float4 va = pa[q], vs = ps[q];
                    gm[q*4+0] += va.x*mk; gm[q*4+1] += va.y*mk;
                    gm[q*4+2] += va.z*mk; gm[q*4+3] += va.w*mk;
                    gs[q*4+0] += vs.x*mk; gs[q*4+1] += vs.y*mk;
                    gs[q*4+2] += vs.z*mk; gs[q*4+3] += vs.w*mk;
                }
            }
        }
        __syncthreads();
    }
    size_t row = (size_t)slot * KTOT;
    float inv = 1.f / fmaxf((float)nE, 1.f);
    if (tid < 200){
        #pragma unroll
        for (int b = 0; b < NB; ++b){
            Gm[row + b*200 + tid] = f2b(gm[b] * inv);
            Gs[row + b*200 + tid] = f2b(gs[b] * inv);
        }
    }
    if (tid < 100){
        float xv = (slot < UCNT) ? unseen[(size_t)slot*DE + tid] : 0.f;
        unsigned short h = f2b(xv);
        Gm[row + 3200 + tid] = h; Gs[row + 3200 + tid] = h;
    } else if (tid == 100){
        Gm[row + 3300] = f2b(1.f); Gs[row + 3300] = f2b(1.f);
    } else if (tid > 100 && tid < 128){
        Gm[row + 3200 + tid] = 0; Gs[row + 3200 + tid] = 0;   // 3301..3327
    }
}

// ---- K5: agg = G_aug @ B_aug (bf16 MFMA), both branches ----
__global__ __launch_bounds__(256) void k_gemm(
        const unsigned short* __restrict__ Gm, const unsigned short* __restrict__ Gs,
        const unsigned short* __restrict__ Btm, const unsigned short* __restrict__ Bts,
        float* __restrict__ aggm, float* __restrict__ aggs){
    int wid = blockIdx.x * 4 + (threadIdx.x >> 6);     // 0..447
    int lane = threadIdx.x & 63;
    int br = wid / 224;
    int w2 = wid % 224;
    int m16 = w2 & 31;                                  // 32 M-tiles of 16 rows
    int jt  = w2 >> 5;                                  // 7 j-tiles
    const unsigned short* A  = br ? Gs : Gm;
    const unsigned short* Bt = br ? Bts : Btm;
    float* agg = br ? aggs : aggm;
    int rowa = lane & 15, ko = (lane >> 4) * 8;
    int j0 = (jt == 6) ? 84 : jt*16;                    // overlap trick, guard col>=96
    int col = j0 + rowa;
    const unsigned short* ap = A  + (size_t)(m16*16 + rowa)*KTOT + ko;
    const unsigned short* bp = Bt + (size_t)col*KTOT + ko;
    f32x4 acc = {0.f, 0.f, 0.f, 0.f};
    #pragma unroll 8
    for (int kc = 0; kc < KCH; ++kc){
        short8 av = *(const short8*)(ap + kc*32);
        short8 bv = *(const short8*)(bp + kc*32);
        acc = __builtin_amdgcn_mfma_f32_16x16x32_bf16(av, bv, acc, 0, 0, 0);
    }
    if (jt < 6 || col >= 96){
        int r0 = m16*16 + (lane >> 4)*4;
        #pragma unroll
        for (int r = 0; r < 4; ++r){
            int row = r0 + r;
            if (row < UCNT) agg[(size_t)row*DOUT + col] = acc[r];
        }
    }
}

// ---- K6: gather agg rows to the 3 output blocks ----
__global__ void k_final(const int* __restrict__ unseen_index, const int* __restrict__ ovr,
                        const float* __restrict__ aggm, const float* __restrict__ aggs,
                        float* __restrict__ out){
    int u = blockIdx.x;
    int slot = ovr[unseen_index[u]];
    int j = threadIdx.x;
    if (j < 100){
        float vm = aggm[(size_t)slot*DOUT + j];
        out[(size_t)u*100 + j] = vm;
        out[(size_t)UCNT*100 + (size_t)u*100 + j] = vm;
        out[(size_t)2*UCNT*100 + (size_t)u*100 + j] = aggs[(size_t)slot*DOUT + j];
    }
}

extern "C" void kernel_launch(void* const* d_in, const int* in_sizes, int n_in,
                              void* d_out, int out_size, void* d_ws, size_t ws_size,
                              hipStream_t stream){
    const float* ent        = (const float*)d_in[0];
    const float* rel_table  = (const float*)d_in[1];
    const float* unseen_emb = (const float*)d_in[2];
    const float* att_mu     = (const float*)d_in[3];
    const float* basis_mu   = (const float*)d_in[4];
    const float* root_mu    = (const float*)d_in[5];
    const float* bias_mu    = (const float*)d_in[6];
    const float* att_sig    = (const float*)d_in[7];
    const float* basis_sig  = (const float*)d_in[8];
    const float* root_sig   = (const float*)d_in[9];
    const float* bias_sig   = (const float*)d_in[10];
    const int* node_id      = (const int*)d_in[11];
    const int* edge_index   = (const int*)d_in[12];
    const int* edge_type    = (const int*)d_in[13];
    const int* rel_index    = (const int*)d_in[14];
    const int* unseen_index = (const int*)d_in[15];
    float* out = (float*)d_out;
    char* ws = (char*)d_ws;

    int* ovr   = (int*)(ws + OFF_OVR);
    int* scnt  = (int*)(ws + OFF_SCNT);
    int* elist = (int*)(ws + OFF_EL2);
    unsigned short* Gm  = (unsigned short*)(ws + OFF_GM);
    unsigned short* Gs  = (unsigned short*)(ws + OFF_GS);
    unsigned short* Btm = (unsigned short*)(ws + OFF_BTM);
    unsigned short* Bts = (unsigned short*)(ws + OFF_BTS);
    float* aggm = (float*)(ws + OFF_AGM);
    float* aggs = (float*)(ws + OFF_AGS);

    k_init<<<TR_BLOCKS + OVR_BLOCKS + 1, 256, 0, stream>>>(
        ovr, scnt, basis_mu, basis_sig, root_mu, root_sig, bias_mu, bias_sig, Btm, Bts);
    k_scatter<<<1, 512, 0, stream>>>(unseen_index, ovr);
    k_filter<<<(E2V + 255)/256, 256, 0, stream>>>(edge_index, ovr, scnt, elist);
    k_g<<<MROWS, 256, 0, stream>>>(scnt, elist, ovr, edge_index, edge_type,
        rel_index, node_id, ent, unseen_emb, rel_table, att_mu, att_sig, Gm, Gs);
    k_gemm<<<112, 256, 0, stream>>>(Gm, Gs, Btm, Bts, aggm, aggs);
    k_final<<<UCNT, 128, 0, stream>>>(unseen_index, ovr, aggm, aggs, out);
}